// Round 14
// baseline (236.778 us; speedup 1.0000x reference)
//
#include <hip/hip_runtime.h>
#include <stdint.h>

// Problem constants
#define BB   2048
#define DIN  2048
#define UU   1024
#define KF   49
#define GM   2048         // GEMM M = batch
#define GK   3072         // GEMM K = UU + DIN
#define GN   5120         // GEMM N = 5*UU

// GEMM block geometry: 64 rows x 32 ucols x 5 gates, 256 threads (4 waves 2x2)
#define BKS  32           // K per step (96 steps)
#define SZB  14336        // bytes per LDS buffer: A 4KB + B 10KB; 2 buffers = 28KB
                          // -> 4 blocks/CU x 4 waves = 16 waves/CU (TLP lever)

typedef __bf16  bf16x8 __attribute__((ext_vector_type(8)));
typedef float   f32x4  __attribute__((ext_vector_type(4)));

#define VL(dst, ptr) asm volatile("global_load_dwordx4 %0, %1, off" \
                                  : "=v"(dst) : "v"(ptr) : "memory")

static __device__ __forceinline__ unsigned short f2bf(float f) {
    union { float f; unsigned u; } x; x.f = f;
    unsigned u = x.u;
    unsigned r = (u + 0x7fffu + ((u >> 16) & 1u)) >> 16;   // RNE
    return (unsigned short)r;
}

// ---------------------------------------------------------------------------
// Kernel 1: prep = buildA (blocks [0,6144)) + buildW transpose (rest)
//   A[b][k]  = bf16([h_tm | inputs])                             [GM][GK]
//   Wt[n][k] = bf16(k<UU ? W_gates[k][n] : U_gates[k-UU][n])     [GN][GK]
// ---------------------------------------------------------------------------
__global__ void prep(const float* __restrict__ h, const float* __restrict__ x,
                     const float* __restrict__ Wg, const float* __restrict__ Ug,
                     unsigned short* __restrict__ A, unsigned short* __restrict__ Wt) {
    __shared__ float t[32][36];
    if (blockIdx.x < 6144) {
        int idx = blockIdx.x * 256 + threadIdx.x;    // one thread = 4 elems
        int b = idx / (GK / 4);
        int k = (idx % (GK / 4)) * 4;
        float4 v;
        if (k < UU) v = *(const float4*)(h + (size_t)b * UU + k);
        else        v = *(const float4*)(x + (size_t)b * DIN + (k - UU));
        ushort4 o;
        o.x = f2bf(v.x); o.y = f2bf(v.y); o.z = f2bf(v.z); o.w = f2bf(v.w);
        *(ushort4*)(A + (size_t)idx * 4) = o;
    } else {
        int bid2 = blockIdx.x - 6144;                // 32x32 transpose tiles
        int k0 = (bid2 % (GK / 32)) * 32;
        int n0 = (bid2 / (GK / 32)) * 32;
        int r  = threadIdx.x >> 3;                   // 0..31
        int cq = threadIdx.x & 7;                    // 0..7  (x4 floats)
        int k = k0 + r;
        const float* src = (k < UU) ? (Wg + (size_t)k * GN) : (Ug + (size_t)(k - UU) * GN);
        *(float4*)&t[r][cq * 4] = *(const float4*)(src + n0 + cq * 4);
        __syncthreads();
        ushort4 o;
        o.x = f2bf(t[cq * 4 + 0][r]);
        o.y = f2bf(t[cq * 4 + 1][r]);
        o.z = f2bf(t[cq * 4 + 2][r]);
        o.w = f2bf(t[cq * 4 + 3][r]);
        *(ushort4*)(Wt + (size_t)(n0 + r) * GK + k0 + cq * 4) = o;
    }
}

// ---------------------------------------------------------------------------
// Kernel 2: HIGH-OCCUPANCY fused 5-gate GEMM + v_seq reduction + LSTM tail.
// 1024 blocks of 256 threads (4 waves 2x2), tile 64 rows x 32 ucols x 5 gates,
// 28KB LDS -> 4 independent blocks/CU (16 waves/CU): one block's vmcnt(0)
// drain overlaps the other blocks' MFMA/ds_read (the latency-bound signature
// of R11's counters -- occupancy was the untried axis).
// Per step t: STAGE(t+1)->buf^1 (4 uniform gload_lds) -> VL v(t+1) ->
//   COMPUTE(t) -> consume v(t) -> vmcnt(0) -> s_barrier -> sched_barrier.
// v coverage: step t handles (k = t>>1, half = t&1); k=48 in epilogue.
// ---------------------------------------------------------------------------
__global__ __launch_bounds__(256, 4) void gemm_fused(
        const unsigned short* __restrict__ A, const unsigned short* __restrict__ Wt,
        const float* __restrict__ m_tm, const float* __restrict__ bg,
        const float* __restrict__ v_seq, float* __restrict__ out) {
    __shared__ __align__(16) char lds[2 * SZB];      // 28,672 B

    const int tid  = threadIdx.x;
    const int lane = tid & 63;
    const int wave = tid >> 6;          // 0..3
    const int wr = wave >> 1, wc = wave & 1;
    const int brow  = (blockIdx.x >> 5) * 64;        // 32 row-tiles
    const int ucol0 = (blockIdx.x & 31) * 32;        // 32 ucol-tiles

    f32x4 acc[2][5];
#pragma unroll
    for (int m = 0; m < 2; m++)
#pragma unroll
        for (int g = 0; g < 5; g++) acc[m][g] = (f32x4){0.f, 0.f, 0.f, 0.f};

    // staging: 896 chunks of 16B per K-step (A 256, B 640), 4 uniform rounds
    // (round 3 duplicated across thread halves) -- R11-verified map.
    const unsigned short* src[4];
    int ldsoff[4];
#pragma unroll
    for (int r = 0; r < 4; ++r) {
        if (r == 0) {
            int j = tid;
            src[r] = A + (size_t)(brow + (j >> 2)) * GK + (j & 3) * 8;
            ldsoff[r] = j * 16;
        } else {
            int j2 = (r < 3) ? (r - 1) * 256 + tid : 512 + (tid & 127);
            int g = j2 >> 7;                         // rB = j2>>2 = g*32+nn
            int nn = (j2 >> 2) & 31;
            int c = j2 & 3;
            src[r] = Wt + ((size_t)g * UU + ucol0 + nn) * GK + c * 8;
            ldsoff[r] = 4096 + j2 * 16;
        }
    }

    // fragment read offsets (R11-verified)
    int aoff[2], boff[5];
#pragma unroll
    for (int m = 0; m < 2; m++)
        aoff[m] = (wr * 32 + m * 16 + (lane & 15)) * 64 + (lane >> 4) * 16;
#pragma unroll
    for (int g = 0; g < 5; g++)
        boff[g] = 4096 + (g * 32 + wc * 16 + (lane & 15)) * 64 + (lane >> 4) * 16;

    auto STAGE = [&](int kstep, int bufb) {
        const int ko = kstep * BKS;
#pragma unroll
        for (int r = 0; r < 4; ++r)
            __builtin_amdgcn_global_load_lds(
                (const __attribute__((address_space(1))) void*)(src[r] + ko),
                (__attribute__((address_space(3))) void*)(lds + bufb + ldsoff[r]), 16, 0, 0);
    };
    auto COMPUTE = [&](int bufb) {
        bf16x8 af[2], bfr[5];
#pragma unroll
        for (int m = 0; m < 2; m++) af[m]  = *(const bf16x8*)(lds + bufb + aoff[m]);
#pragma unroll
        for (int g = 0; g < 5; g++) bfr[g] = *(const bf16x8*)(lds + bufb + boff[g]);
#pragma unroll
        for (int m = 0; m < 2; m++)
#pragma unroll
            for (int g = 0; g < 5; g++)
                acc[m][g] = __builtin_amdgcn_mfma_f32_16x16x32_bf16(af[m], bfr[g], acc[m][g], 0, 0, 0);
    };

    // v_seq: thread covers row tid>>2, 8 cols at (tid&3)*8; per step one f32x4:
    // step t -> k=t>>1, half=t&1 (half 0: cols +0..3 -> sa; half 1: +4..7 -> sb)
    const float* vp = v_seq + (size_t)(brow + (tid >> 2)) * (KF * UU)
                    + ucol0 + (tid & 3) * 8;
    f32x4 sa = {0,0,0,0}, sb = {0,0,0,0};
    f32x4 XA, XB;                        // even-step / odd-step in-flight loads

    // prologue: STAGE(0), VL v(step0); drain; barrier
    STAGE(0, 0);
    VL(XA, vp);                          // k=0, half=0
    asm volatile("s_waitcnt vmcnt(0)" ::: "memory");
    __builtin_amdgcn_s_barrier();
    __builtin_amdgcn_sched_barrier(0);

    int buf = 0;
    for (int tp = 0; tp < 48; ++tp) {
        {   // even t=2tp: stage t+1, VL v(t+1)=k(tp) half1, compute, consume XA
            STAGE(2 * tp + 1, buf ^ SZB);
            VL(XB, vp + (size_t)tp * UU + 4);
            COMPUTE(buf);
            sa += XA;
            asm volatile("s_waitcnt vmcnt(0)" ::: "memory");
            __builtin_amdgcn_s_barrier();
            __builtin_amdgcn_sched_barrier(0);
            buf ^= SZB;
        }
        {   // odd t=2tp+1: stage t+1 (if any), VL v(t+1)=k(tp+1) half0, compute, consume XB
            if (tp < 47) {
                STAGE(2 * tp + 2, buf ^ SZB);
                VL(XA, vp + (size_t)(tp + 1) * UU);
            }
            COMPUTE(buf);
            sb += XB;
            if (tp < 47) {
                asm volatile("s_waitcnt vmcnt(0)" ::: "memory");
                __builtin_amdgcn_s_barrier();
                __builtin_amdgcn_sched_barrier(0);
            }
            buf ^= SZB;
        }
    }

    // leftover v_seq k = 48 (both halves; pipeline drained)
    sa += *(const f32x4*)(vp + (size_t)48 * UU);
    sb += *(const f32x4*)(vp + (size_t)48 * UU + 4);

    // exchange v-sums via LDS: lv[64][36] floats (9.2KB, reuses buffer 0)
    __syncthreads();                     // all waves done with LDS buffers
    float* lv = (float*)lds;
    {
        const int r = tid >> 2, c = (tid & 3) * 8;
        *(f32x4*)&lv[(size_t)r * 36 + c]     = sa;
        *(f32x4*)&lv[(size_t)r * 36 + c + 4] = sb;
    }
    __syncthreads();

    // Epilogue: gates + cell + sentinel + ct, write 3 outputs.
    const int ucol = ucol0 + wc * 16 + (lane & 15);
    const int lcol = wc * 16 + (lane & 15);
    const float b0 = bg[0 * UU + ucol];
    const float b1 = bg[1 * UU + ucol];
    const float b2 = bg[2 * UU + ucol];
    const float b3 = bg[3 * UU + ucol];
    const float b4 = bg[4 * UU + ucol];
    const int lr0 = wr * 32 + ((lane >> 4) << 2);
    float* out0 = out;
    float* out1 = out + (size_t)GM * UU;
    float* out2 = out + 2 * (size_t)GM * UU;
#pragma unroll
    for (int m = 0; m < 2; m++) {
#pragma unroll
        for (int j = 0; j < 4; j++) {
            const int lrow = lr0 + m * 16 + j;
            const int row  = brow + lrow;
            const size_t idx = (size_t)row * UU + ucol;
            const float vs  = lv[(size_t)lrow * 36 + lcol];
            const float mtm = m_tm[idx];
            const float f = acc[m][0][j] + b0;
            const float i = acc[m][1][j] + b1;
            const float o = acc[m][2][j] + b2;
            const float g = acc[m][3][j] + b3;
            const float a = acc[m][4][j] + b4;
            const float ft = 1.f / (1.f + __expf(-f));
            const float it = 1.f / (1.f + __expf(-i));
            const float ot = 1.f / (1.f + __expf(-o));
            const float gt = 1.f / (1.f + __expf(-g));
            const float at = tanhf(a);
            const float mtv = mtm * ft + it * at;
            const float tm  = tanhf(mtv);
            const float ht  = ot * tm;
            const float st  = gt * tm;
            out0[idx] = ht + vs + st;
            out1[idx] = ht;
            out2[idx] = mtv;
        }
    }
}

// ---------------------------------------------------------------------------
extern "C" void kernel_launch(void* const* d_in, const int* in_sizes, int n_in,
                              void* d_out, int out_size, void* d_ws, size_t ws_size,
                              hipStream_t stream) {
    (void)in_sizes; (void)n_in; (void)out_size; (void)ws_size;
    const float* inputs  = (const float*)d_in[0];
    const float* h_tm    = (const float*)d_in[1];
    const float* m_tm    = (const float*)d_in[2];
    const float* v_seq   = (const float*)d_in[3];
    const float* W_gates = (const float*)d_in[4];
    const float* U_gates = (const float*)d_in[5];
    const float* b_gates = (const float*)d_in[6];
    // d_in[7..9] (W_z, U_z, W_h) are dead: softmax over a size-1 axis == 1.

    char* ws = (char*)d_ws;
    unsigned short* Abf = (unsigned short*)ws;                  // 2048*3072*2 = 12,582,912 B
    unsigned short* Wt  = (unsigned short*)(ws + 12582912);     // 5120*3072*2 = 31,457,280 B
    float* out = (float*)d_out;

    hipLaunchKernelGGL(prep, dim3(6144 + (GK / 32) * (GN / 32)), dim3(256), 0, stream,
                       h_tm, inputs, W_gates, U_gates, Abf, Wt);
    hipLaunchKernelGGL(gemm_fused, dim3(1024), dim3(256), 0, stream,
                       Abf, Wt, m_tm, b_gates, v_seq, out);
}